// Round 7
// baseline (321.736 us; speedup 1.0000x reference)
//
#include <hip/hip_runtime.h>

typedef unsigned int uint;
typedef __bf16 bf16_t;
typedef bf16_t bf16x8 __attribute__((ext_vector_type(8)));
typedef float floatx4 __attribute__((ext_vector_type(4)));

struct __align__(8) us4 { unsigned short x, y, z, w; };

__device__ __forceinline__ unsigned short f2b(float f) {
    unsigned u = __float_as_uint(f);
    u = u + 0x7FFFu + ((u >> 16) & 1u);   // RNE
    return (unsigned short)(u >> 16);
}
__device__ __forceinline__ float b2f(unsigned short h) {
    return __uint_as_float(((unsigned)h) << 16);
}

// async global->LDS, 16B per lane; LDS dest is wave-uniform base + lane*16
__device__ __forceinline__ void g2l16(const void* g, void* l) {
    __builtin_amdgcn_global_load_lds((__attribute__((address_space(1))) void*)g,
                                     (__attribute__((address_space(3))) void*)l,
                                     16, 0, 0);
}

// ---------------------------------------------------------------------------
// gemm256x128 (R7): O[m,n] = sum_k A[m,k]*B[n,k], K=512 (16 K-tiles, BK=32).
// Tile 256x128, 256 threads = 4 waves (2M x 2N), wave-tile 128x64, acc[8][4].
// Same proven R3 skeleton: 3-deep LDS ring (24KB/buf = 72KB -> 2 blocks/CU),
// counted vmcnt, 2-way-free XOR swizzle, setprio around MFMA.
//
// Why this geometry: R3 (wave 64x64) was LDS-BW-bound -- per CU per K-tile
// 176KB LDS traffic (704cy) vs 310cy MFMA => 44% ceiling, 30% measured.
// Wave 128x64 reads 12KB/wave feeding 32 MFMAs (42.7 FLOP/LDS-byte vs 32):
// per CU 144KB (576cy) vs 310cy => 54% ceiling. Same wave geometry as
// HipKittens' 62%-MfmaUtil 256^2 kernel.
// Registers (R5 lesson): acc 128 + af 32 + bv 16 + ~25 addr ~= 200 < 256
// class; __launch_bounds__(256,2) -> 8 waves/CU = 2 independent blocks.
//
// Per K-tile t: { stage tile t+2 into buf (t+2)%3 (6 x g2l16/thread: 4 A-
//   chunks + 2 B-chunks); ds_read af[8]+bv[4]; setprio(1); 32 MFMA;
//   setprio(0); vmcnt(6) (counted: t+2's 6 loads stay in flight); barrier }.
// Tail: t=14 waits vmcnt(0), t=15 no trailing sync.
//
// LDS buffer: A rows 0..255 (16KB), B rows 0..127 at byte 16384 (8KB);
// 64B/row, 16B-chunk swizzle chunk' = chunk ^ ((row>>1)&3) (2-way, free).
// Stage keeps linear LDS dest; SOURCE pre-swizzled; ds_read applies XOR.
//
// Grid (MODE != 6): 1-D, XCD swizzle id&7, g=id>>3, nt=g%NTN, ms=(g/NTN)*8+xcd.
// BMS: ms decodes (batch = ms&7, mtile = ms>>3) -> batch pinned to XCD.
// MODE 0: bf16 store
// MODE 3: f32 store of acc + R (residual)
// MODE 5: bf16 store of acc*(scale/Sn[row]) + R   (attn: fused q-softmax)
// MODE 4: fused qkv, B=concat(Wq,Wk,Wv)[1536x512], n-tiles 128 wide:
//   n0<512    : store exp(acc) -> O (=eq), atomicAdd row sums into Sq[m]
//   512..1023 : store exp(acc) transposed -> O2 (=ekT[b,d,n]), atomicAdd
//               column sums into Sk[b*512+d]
//   >=1024    : store acc transposed -> O3 (=vT[b,e,n])
// MODE 6: ctx split-K partial. grid 512: xcd=id&7, g=id>>3; t8=g&7 ->
//   mt=t8>>2 (0..1), ntc=t8&3 (0..3); slice=(g>>3)*8+xcd = b*8+sk.
//   A=vT[b, mt*256.., sk*512..], B=kT[b, ntc*128.., sk*512..], f32 store of
//   the 256x128 partial into P[slice*262144 + (mt*256+r)*512 + ntc*128 + c].
// ---------------------------------------------------------------------------
template <int MODE, int NTN, bool BMS, int LD>
__global__ __launch_bounds__(256, 2) void gemm256x128(
    const unsigned short* __restrict__ A, const unsigned short* __restrict__ B,
    void* __restrict__ O, const unsigned short* __restrict__ R,
    unsigned short* __restrict__ O2, unsigned short* __restrict__ O3,
    float* __restrict__ Sq, float* __restrict__ Sk,
    const float* __restrict__ Sn,
    long long sB, float scale)
{
    __shared__ __attribute__((aligned(16))) unsigned short Ls[3][12288]; // 72 KB

    const uint id = blockIdx.x;
    const int tid = threadIdx.x;
    const int l = tid & 63;
    const int w = tid >> 6;           // 0..3
    const int wm = (w >> 1) * 128;    // 0/128 : M-half of the 256-row tile
    const int wnb = (w & 1) * 64;     // 0/64  : N-strip of the 128-col tile

    int arow0 = 0, n0 = 0, bb = 0;
    const unsigned short* Ab;
    const unsigned short* Bbp;
    long long pbase = 0;

    if constexpr (MODE == 6) {
        const uint xcd = id & 7;
        const uint g = id >> 3;
        const int t8 = (int)(g & 7);
        const int mt = t8 >> 2, ntc = t8 & 3;
        const int slice = (int)(g >> 3) * 8 + (int)xcd;   // = b*8 + sk
        const int b6 = slice >> 3, sk6 = slice & 7;
        Ab  = A + ((long long)b6 * 512 + mt  * 256) * 4096 + sk6 * 512;
        Bbp = B + ((long long)b6 * 512 + ntc * 128) * 4096 + sk6 * 512;
        pbase = (long long)slice * 262144 + (long long)mt * 256 * 512 + ntc * 128;
    } else {
        const uint xcd = id & 7;
        const uint g = id >> 3;
        const uint nt = g % NTN;
        const uint mg = g / NTN;
        const uint ms = mg * 8 + xcd;
        if constexpr (BMS) { bb = (int)(ms & 7); arow0 = bb * 4096 + (int)(ms >> 3) * 256; }
        else               { bb = 0;             arow0 = (int)ms * 256; }
        n0 = (int)nt * 128;
        Ab  = A + (long long)arow0 * LD;
        Bbp = B + (long long)bb * sB + (long long)n0 * LD;
    }

    // ---- staging sources (pre-swizzled). Thread owns LDS 16B chunks
    // {c*256+tid : c=0..3} (A, rows c*64 + tid>>2) and {1024 + c2*256 + tid :
    // c2=0..1} (B, rows c2*64 + tid>>2). For all: slot = tid&3, source chunk
    // lc = (tid&3) ^ ((tid>>3)&3)  (row>>1 & 3 reduces to (tid>>3)&3 since
    // the c*64 row offsets are 0 mod 8).
    const int q_ = tid >> 2;                         // 0..63
    const int lc = (tid & 3) ^ ((tid >> 3) & 3);
    const unsigned short* pA = Ab  + (long long)q_ * LD + lc * 8;
    const unsigned short* pB = Bbp + (long long)q_ * LD + lc * 8;

#define STG(bi, koff) do {                                                  \
        unsigned short* d_ = &Ls[bi][0] + tid * 8;                          \
        g2l16(pA + (koff),                      d_);                        \
        g2l16(pA + (long long) 64 * LD + (koff), d_ + 2048);                \
        g2l16(pA + (long long)128 * LD + (koff), d_ + 4096);                \
        g2l16(pA + (long long)192 * LD + (koff), d_ + 6144);                \
        g2l16(pB + (koff),                      d_ + 8192);                 \
        g2l16(pB + (long long) 64 * LD + (koff), d_ + 10240);               \
    } while (0)

    // ---- ds_read fragment addressing (byte offsets within a buffer)
    const int fr = l & 15;
    const int c0 = l >> 4;
    const int swz = (c0 ^ ((fr >> 1) & 3)) << 4;
    const int aoff = (wm + fr) * 64 + swz;             // + i*1024 (i<8)
    const int boff = 16384 + (wnb + fr) * 64 + swz;    // + j*1024 (j<4)

    floatx4 acc[8][4] = {};

    // prologue: tiles 0,1 staged (12 loads); wait tile 0 (keep 6 in flight)
    STG(0, 0);
    STG(1, 32);
    asm volatile("s_waitcnt vmcnt(6)" ::: "memory");
    __builtin_amdgcn_s_barrier();

    int cur = 0, stb = 2;
    for (int t = 0; t < 16; ++t) {
        if (t + 2 < 16) STG(stb, (t + 2) * 32);

        const char* Lb = (const char*)&Ls[cur][0];
        bf16x8 af[8], bv[4];
#pragma unroll
        for (int i = 0; i < 8; ++i) af[i] = *(const bf16x8*)(Lb + aoff + i * 1024);
#pragma unroll
        for (int j = 0; j < 4; ++j) bv[j] = *(const bf16x8*)(Lb + boff + j * 1024);

        __builtin_amdgcn_s_setprio(1);
#pragma unroll
        for (int i = 0; i < 8; ++i)
#pragma unroll
            for (int j = 0; j < 4; ++j)
                acc[i][j] = __builtin_amdgcn_mfma_f32_16x16x32_bf16(
                    af[i], bv[j], acc[i][j], 0, 0, 0);
        __builtin_amdgcn_s_setprio(0);

        if (t < 15) {
            if (t < 14) asm volatile("s_waitcnt vmcnt(6)" ::: "memory");
            else        asm volatile("s_waitcnt vmcnt(0)" ::: "memory");
            __builtin_amdgcn_s_barrier();
        }
        cur = (cur == 2) ? 0 : cur + 1;
        stb = (stb == 2) ? 0 : stb + 1;
    }
#undef STG

    // C/D layout (verified m89/m91): col = lane&15, row = (lane>>4)*4 + reg
    const int col = l & 15;
    const int rbase = (l >> 4) * 4;
    const int gm0 = arow0 + wm + rbase;           // + i*16 + r
    const int gn0 = n0 + wnb + col;               // + j*16

    if constexpr (MODE == 6) {
        float* Pb = (float*)O + pbase;
#pragma unroll
        for (int i = 0; i < 8; ++i) {
            int lr = wm + i * 16 + rbase;
#pragma unroll
            for (int j = 0; j < 4; ++j) {
                int lcc = wnb + j * 16 + col;
#pragma unroll
                for (int r = 0; r < 4; ++r)
                    Pb[(long long)(lr + r) * 512 + lcc] = acc[i][j][r];
            }
        }
    } else if constexpr (MODE == 4) {
        if (n0 < 512) {
            // q branch: store exp, row-sum atomics
            unsigned short* Oq = (unsigned short*)O;
            float rs[8][4];
#pragma unroll
            for (int i = 0; i < 8; ++i)
#pragma unroll
                for (int r = 0; r < 4; ++r) rs[i][r] = 0.f;
#pragma unroll
            for (int i = 0; i < 8; ++i) {
                int gm = gm0 + i * 16;
#pragma unroll
                for (int j = 0; j < 4; ++j) {
                    int gn = gn0 + j * 16;
#pragma unroll
                    for (int r = 0; r < 4; ++r) {
                        float e = __expf(acc[i][j][r]);
                        rs[i][r] += e;
                        Oq[(long long)(gm + r) * 512 + gn] = f2b(e);
                    }
                }
            }
#pragma unroll
            for (int i = 0; i < 8; ++i)
#pragma unroll
                for (int r = 0; r < 4; ++r) {
                    float v = rs[i][r];
                    v += __shfl_xor(v, 1);
                    v += __shfl_xor(v, 2);
                    v += __shfl_xor(v, 4);
                    v += __shfl_xor(v, 8);
                    if ((l & 15) == 0)
                        atomicAdd(&Sq[gm0 + i * 16 + r], v);
                }
        } else if (n0 < 1024) {
            // k branch: store exp transposed, column-sum atomics
            const int b = arow0 >> 12;
            const int mq0 = (arow0 & 4095) + wm + rbase;
            float cs[4] = {0.f, 0.f, 0.f, 0.f};
#pragma unroll
            for (int i = 0; i < 8; ++i) {
                int mq = mq0 + i * 16;
#pragma unroll
                for (int j = 0; j < 4; ++j) {
                    int d = gn0 + j * 16 - 512;
                    float e0 = __expf(acc[i][j][0]);
                    float e1 = __expf(acc[i][j][1]);
                    float e2 = __expf(acc[i][j][2]);
                    float e3 = __expf(acc[i][j][3]);
                    cs[j] += e0 + e1 + e2 + e3;
                    us4 pk = { f2b(e0), f2b(e1), f2b(e2), f2b(e3) };
                    *(us4*)(O2 + ((long long)b * 512 + d) * 4096 + mq) = pk;
                }
            }
#pragma unroll
            for (int j = 0; j < 4; ++j) {
                float v = cs[j];
                v += __shfl_xor(v, 16);
                v += __shfl_xor(v, 32);
                if (l < 16)
                    atomicAdd(&Sk[b * 512 + gn0 + j * 16 - 512], v);
            }
        } else {
            // v branch: plain transposed store
            const int b = arow0 >> 12;
            const int mq0 = (arow0 & 4095) + wm + rbase;
#pragma unroll
            for (int i = 0; i < 8; ++i) {
                int mq = mq0 + i * 16;
#pragma unroll
                for (int j = 0; j < 4; ++j) {
                    int e_ = gn0 + j * 16 - 1024;
                    us4 pk = { f2b(acc[i][j][0]), f2b(acc[i][j][1]),
                               f2b(acc[i][j][2]), f2b(acc[i][j][3]) };
                    *(us4*)(O3 + ((long long)b * 512 + e_) * 4096 + mq) = pk;
                }
            }
        }
    } else if constexpr (MODE == 5) {
#pragma unroll
        for (int i = 0; i < 8; ++i) {
            int gm = gm0 + i * 16;
            float invs[4];
#pragma unroll
            for (int r = 0; r < 4; ++r) invs[r] = scale / Sn[gm + r];
#pragma unroll
            for (int j = 0; j < 4; ++j) {
                int gn = gn0 + j * 16;
#pragma unroll
                for (int r = 0; r < 4; ++r) {
                    long long idx = (long long)(gm + r) * 512 + gn;
                    ((unsigned short*)O)[idx] =
                        f2b(acc[i][j][r] * invs[r] + b2f(R[idx]));
                }
            }
        }
    } else {
#pragma unroll
        for (int i = 0; i < 8; ++i) {
            int gm = gm0 + i * 16;
#pragma unroll
            for (int j = 0; j < 4; ++j) {
                int gn = gn0 + j * 16;
#pragma unroll
                for (int r = 0; r < 4; ++r) {
                    long long idx = (long long)(gm + r) * 512 + gn;
                    float v = acc[i][j][r];
                    if constexpr (MODE == 0) {
                        ((unsigned short*)O)[idx] = f2b(v);
                    } else {
                        ((float*)O)[idx] = v + b2f(R[idx]);
                    }
                }
            }
        }
    }
}

// ---------------------------------------------------------------------------
// Wg = round_bf16(W2) @ round_bf16(W1), f32 inputs, bf16 out. Numerically
// identical to the old (bf16-convert, then gemm) path. 512 blocks x 256
// threads; thread t owns cols t, t+256 of row n. Enables the FFN fusion
// (x@W1.T)@W2.T = x@(W2@W1).T, deleting one 32768x512x512 GEMM.
// ---------------------------------------------------------------------------
__global__ __launch_bounds__(256) void wg_gemm(
    const float* __restrict__ W2, const float* __restrict__ W1,
    unsigned short* __restrict__ Wg)
{
    const int n = blockIdx.x;
    const int t = threadIdx.x;
    float a0 = 0.f, a1 = 0.f;
    const float* w2r = W2 + n * 512;
#pragma unroll 8
    for (int k = 0; k < 512; ++k) {
        float s = b2f(f2b(w2r[k]));
        a0 += s * b2f(f2b(W1[k * 512 + t]));
        a1 += s * b2f(f2b(W1[k * 512 + t + 256]));
    }
    Wg[n * 512 + t]       = f2b(a0);
    Wg[n * 512 + t + 256] = f2b(a1);
}

// Sum 8 split-K partials, normalize by k-softmax denominator Sk[b*512+d],
// store bf16 ctxT[b, e, d]. P layout: [slice = b*8+sk][512 e][512 d] f32.
__global__ __launch_bounds__(256) void ctx_reduce(const float* __restrict__ P,
                                                  const float* __restrict__ Sk,
                                                  unsigned short* __restrict__ Ct)
{
    long long f = (long long)blockIdx.x * 256 + threadIdx.x;  // 524288 total
    long long base = f * 4;
    int b = (int)(base >> 18);
    int rem = (int)(base & 262143);          // e*512 + d
    int d = rem & 511;
    float4 s = {0.f, 0.f, 0.f, 0.f};
#pragma unroll
    for (int sp = 0; sp < 8; ++sp) {
        float4 v = *(const float4*)(P + (long long)(b * 8 + sp) * 262144 + rem);
        s.x += v.x; s.y += v.y; s.z += v.z; s.w += v.w;
    }
    float4 sk = *(const float4*)(Sk + b * 512 + d);
    us4 o = { f2b(s.x / sk.x), f2b(s.y / sk.y), f2b(s.z / sk.z), f2b(s.w / sk.w) };
    *(us4*)(Ct + (long long)b * 262144 + rem) = o;
}

// ---------------------------------------------------------------------------
// prep: fused {x f32->bf16 (16384 blocks)} + {Wq/Wk/Wv -> wcat (768)} +
// {zero Ssum (36)} = one launch instead of three.
// ---------------------------------------------------------------------------
__global__ __launch_bounds__(256) void prep(
    const float* __restrict__ x, unsigned short* __restrict__ xb,
    const float* __restrict__ Wq, const float* __restrict__ Wk,
    const float* __restrict__ Wv, unsigned short* __restrict__ wcat,
    float* __restrict__ Ssum)
{
    const int bid = blockIdx.x;
    const int t = threadIdx.x;
    if (bid < 16384) {
        long long i = ((long long)bid * 256 + t) * 4;
        float4 v = *(const float4*)(x + i);
        us4 o = { f2b(v.x), f2b(v.y), f2b(v.z), f2b(v.w) };
        *(us4*)(xb + i) = o;
    } else if (bid < 17152) {
        int wb = bid - 16384;
        int which = wb >> 8;                   // 0..2
        const float* src = which == 0 ? Wq : (which == 1 ? Wk : Wv);
        long long i = ((long long)(wb & 255) * 256 + t) * 4;
        float4 v = *(const float4*)(src + i);
        us4 o = { f2b(v.x), f2b(v.y), f2b(v.z), f2b(v.w) };
        *(us4*)(wcat + (long long)which * 262144 + i) = o;
    } else {
        long long i = ((long long)(bid - 17152) * 256 + t) * 4;
        *(float4*)(Ssum + i) = make_float4(0.f, 0.f, 0.f, 0.f);
    }
}

// ---------------------------------------------------------------------------
extern "C" void kernel_launch(void* const* d_in, const int* in_sizes, int n_in,
                              void* d_out, int out_size, void* d_ws, size_t ws_size,
                              hipStream_t stream)
{
    (void)in_sizes; (void)n_in; (void)out_size; (void)ws_size;
    const float* x  = (const float*)d_in[0];
    const float* Wq = (const float*)d_in[1];
    const float* Wk = (const float*)d_in[2];
    const float* Wv = (const float*)d_in[3];
    const float* W1 = (const float*)d_in[4];
    const float* W2 = (const float*)d_in[5];
    float* out = (float*)d_out;

    const int Bn = 8, N = 4096, C = 512;
    const long long M  = (long long)Bn * N;   // 32768
    const long long XE = M * C;               // 16,777,216 elements

    char* ws = (char*)d_ws;
    size_t off = 0;
    auto carve = [&](size_t bytes) -> void* {
        void* p = ws + off;
        off += (bytes + 255) & ~(size_t)255;
        return p;
    };

    unsigned short* xb   = (unsigned short*)carve(XE * 2);
    unsigned short* wcat = (unsigned short*)carve((size_t)3 * C * C * 2); // [Wq;Wk;Wv]
    unsigned short* wgb  = (unsigned short*)carve((size_t)C * C * 2);     // W2@W1
    unsigned short* q    = (unsigned short*)carve(XE * 2);   // exp(q)
    unsigned short* kT   = (unsigned short*)carve(XE * 2);   // exp(k) [b,d,n]
    unsigned short* vT   = (unsigned short*)carve(XE * 2);   // [b,e,n]
    unsigned short* ctxT = (unsigned short*)carve((size_t)Bn * C * C * 2); // [b,e,d]
    float* Ssum = (float*)carve((size_t)(M + Bn * C) * 4);   // Sq[M] ++ Sk[Bn*C]
    float* Sq = Ssum;
    float* Sk = Ssum + M;
    unsigned short* xr = kT;       // alias: kT dead after ctx gemm
    float* P = (float*)d_out;      // split-K partials (64 slices x 1MB = 64MB
                                   // = d_out): scratch until the final gemm
                                   // overwrites all of it

    // fused conversions + zero (1 launch)
    prep<<<dim3(17188), 256, 0, stream>>>(x, xb, Wq, Wk, Wv, wcat, Ssum);

    // Wg = W2 @ W1 (FFN fusion; reads f32, rounds through bf16 internally)
    wg_gemm<<<dim3(512), 256, 0, stream>>>(W2, W1, wgb);

    // fused q/k/v + exp + softmax-denominator atomics: M=32768, N=1536
    // 256x128 tiles: 128 m x 12 n = 1536 blocks (2 blocks/CU co-resident)
    gemm256x128<4, 12, false, 512><<<dim3(1536), 256, 0, stream>>>(
        xb, wcat, q, nullptr, kT, vT, Sq, Sk, nullptr, 0, 0.f);

    // ctxT'[b,e,d] = sum_n vT[b,e,n] * ek[b,d,n]  (split-K=8 + reduce w/ 1/Sk)
    gemm256x128<6, 1, false, 4096><<<dim3(512), 256, 0, stream>>>(
        vT, kT, P, nullptr, nullptr, nullptr, nullptr, nullptr, nullptr,
        0, 0.f);
    ctx_reduce<<<dim3(2048), 256, 0, stream>>>(P, Sk, ctxT);

    // xr[b,n,e] = (scale/Sq[n]) * sum_d eq[b,n,d]*ctxT[b,e,d] + x[b,n,e]
    gemm256x128<5, 4, true, 512><<<dim3(512), 256, 0, stream>>>(
        q, ctxT, xr, xb, nullptr, nullptr, nullptr, nullptr, Sq,
        (long long)C * C, 0.044194173824159216f);

    // out = xr @ Wg.T + xr   (fp32 output; residual exact via MODE 3)
    gemm256x128<3, 4, false, 512><<<dim3(512), 256, 0, stream>>>(
        xr, wgb, out, xr, nullptr, nullptr, nullptr, nullptr, nullptr,
        0, 0.f);
}